// Round 7
// baseline (39.650 us; speedup 1.0000x reference)
//
#include <hip/hip_runtime.h>
#include <hip/hip_bf16.h>

// Problem constants
#define PM 8        // groups
#define PK 4096     // codebook entries per group
#define PD 128      // dim
#define PN 8
#define PH 64
#define PW 64

typedef __attribute__((ext_vector_type(8))) short bf16x8;
typedef __attribute__((ext_vector_type(4))) float f32x4;
typedef __attribute__((ext_vector_type(8))) short short8v;

__device__ inline unsigned short f2bf_rne(float f) {
    unsigned int u = __float_as_uint(f);
    unsigned int r = (u + 0x7FFFu + ((u >> 16) & 1u)) >> 16;
    return (unsigned short)r;
}
__device__ inline float bf2f(unsigned short s) {
    return __uint_as_float(((unsigned int)s) << 16);
}

__device__ inline bf16x8 loadcvt8(const float* __restrict__ p) {
    f32x4 x0 = *(const f32x4*)p;
    f32x4 x1 = *(const f32x4*)(p + 4);
    bf16x8 r;
#pragma unroll
    for (int j = 0; j < 4; ++j) {
        r[j]     = (short)f2bf_rne(x0[j]);
        r[j + 4] = (short)f2bf_rne(x1[j]);
    }
    return r;
}

// ---------------------------------------------------------------------------
// Kernel 1 v3 (unchanged from R5, ~4 us): table[m,k,c] via LDS-staged wq,
// swapped-operand MFMA, packed 8 B stores.
// ---------------------------------------------------------------------------
__global__ __launch_bounds__(256) void build_table(
        const float* __restrict__ codebook,
        const float* __restrict__ wq,
        const float* __restrict__ bq,
        unsigned short* __restrict__ table) {
    __shared__ unsigned short ldsA[2048 * 8];   // 2048 frag-units x 16 B = 32 KB
    __shared__ float lds_bq[PD];
    const int b = blockIdx.x;
    const int m = b & 7;
    const int kt0 = (b >> 3) * 128;
    const int tid = threadIdx.x;
    const int wv = tid >> 6;
    const int l  = tid & 63;
    const int lr = l & 15;
    const int lg = l >> 4;

    const float* cb = codebook + (size_t)m * PK * PD;
    const float* wm = wq + (size_t)m * PD * PD;

    if (tid < PD) lds_bq[tid] = bq[m * PD + tid];

    // Stage wq -> LDS frag-major: unit u = (cs<<4)|(kk<<2)|lg holds
    // wq[cs*16 + slot][kk*32 + lg*8 .. +8) as bf16x8 at slot index.
    {
        const int lr_s = tid & 15;
        const int u0 = (tid >> 4) * 8;
#pragma unroll
        for (int i = 0; i < 8; ++i) {
            const int u  = u0 + i;
            const int cs = u >> 4;
            const int kk = (u >> 2) & 3;
            const int lgs = u & 3;
            bf16x8 v = loadcvt8(wm + (size_t)(cs * 16 + lr_s) * PD + kk * 32 + lgs * 8);
            *(bf16x8*)&ldsA[(size_t)(u * 16 + lr_s) * 8] = v;
        }
    }

    // Codebook B-frags (per-wave k rows), loaded while staging is in flight.
    bf16x8 bfragc[2][4];
#pragma unroll
    for (int ks = 0; ks < 2; ++ks) {
        const int k = kt0 + wv * 32 + ks * 16 + lr;
        const float* src = cb + (size_t)k * PD + lg * 8;
#pragma unroll
        for (int kk = 0; kk < 4; ++kk) {
            bfragc[ks][kk] = loadcvt8(src + kk * 32);
        }
    }
    __syncthreads();

#pragma unroll
    for (int cs = 0; cs < 8; ++cs) {
        bf16x8 afragw[4];
#pragma unroll
        for (int kk = 0; kk < 4; ++kk) {
            const int u = (cs << 4) | (kk << 2) | lg;
            afragw[kk] = *(const bf16x8*)&ldsA[(size_t)(u * 16 + lr) * 8];
        }
        const f32x4 bias4 = *(const f32x4*)&lds_bq[cs * 16 + lg * 4];
#pragma unroll
        for (int ks = 0; ks < 2; ++ks) {
            f32x4 acc = {0.f, 0.f, 0.f, 0.f};
#pragma unroll
            for (int kk = 0; kk < 4; ++kk) {
                acc = __builtin_amdgcn_mfma_f32_16x16x32_bf16(
                        afragw[kk], bfragc[ks][kk], acc, 0, 0, 0);
            }
            // D[row = c = cs*16 + lg*4 + j][col = k = kt0+wv*32+ks*16+lr]
            const int k = kt0 + wv * 32 + ks * 16 + lr;
            unsigned int p0 = (unsigned int)f2bf_rne(acc[0] + bias4[0])
                            | ((unsigned int)f2bf_rne(acc[1] + bias4[1]) << 16);
            unsigned int p1 = (unsigned int)f2bf_rne(acc[2] + bias4[2])
                            | ((unsigned int)f2bf_rne(acc[3] + bias4[3]) << 16);
            uint2 pk; pk.x = p0; pk.y = p1;
            *(uint2*)&table[((size_t)(m * PK + k)) * PD + cs * 16 + lg * 4] = pk;
        }
    }
}

// ---------------------------------------------------------------------------
// Kernel 2 v6: cooperative gather + DIRECT stores (R6 minus the LDS round
// trip — the clean test of TCP same-line lane-coalescing).
// Thread (p = tid>>2, sub = tid&3): reads 16 B chunks i=0..3 at
//   row + i*64B + sub*16B -> for fixed i, the 4 sub-lanes cover ONE 64 B
//   line of position p's row => gather instr = 16 distinct lines (vs 64 in
//   the per-lane-random layout). Code load: 4 lanes/address broadcast.
// Thread holds c = i*32 + sub*8 + j (bijective over 0..127 with i,sub,j).
// Store instr (i,j): 4 c-planes x 16 consecutive w x 4 B = 4 full 64 B
//   segments — same resolve count as the proven R1 store pattern.
// No LDS, no sync, low VGPR -> high occupancy for read/write overlap.
// m = b&7 keeps each XCD on its 1 MB table slice.
// ---------------------------------------------------------------------------
__global__ __launch_bounds__(256) void gather_scatter(
        const int* __restrict__ codes,
        const unsigned short* __restrict__ table,
        float* __restrict__ out) {
    const int b = blockIdx.x;
    const int m = b & 7;
    const int rest = b >> 3;
    const int n = rest >> 6;
    const int h = rest & 63;
    const int tid = threadIdx.x;
    const int p   = tid >> 2;   // position (w) 0..63
    const int sub = tid & 3;    // 16 B sub-chunk within each 64 B line

    const int code = codes[((n * PH + h) * PW + p) * PM + m];
    const unsigned short* row = table + ((size_t)m * PK + code) * PD;

    short8v v[4];
#pragma unroll
    for (int i = 0; i < 4; ++i) {
        v[i] = *(const short8v*)(row + i * 32 + sub * 8);
    }

    // out[n, m*128 + c, h, w=p], c = i*32 + sub*8 + j
    float* ob = out + (((size_t)n * (PM * PD) + m * PD + sub * 8) * PH + h) * PW + p;
#pragma unroll
    for (int i = 0; i < 4; ++i) {
#pragma unroll
        for (int j = 0; j < 8; ++j) {
            ob[(size_t)(i * 32 + j) * (PH * PW)] = bf2f((unsigned short)v[i][j]);
        }
    }
}

// ---------------------------------------------------------------------------
// Fallback (only if ws_size < table size): fused direct compute, fp32.
// ---------------------------------------------------------------------------
__global__ __launch_bounds__(256) void fused_direct(
        const int* __restrict__ codes,
        const float* __restrict__ codebook,
        const float* __restrict__ wq,
        const float* __restrict__ bq,
        float* __restrict__ out) {
    __shared__ float rows[PW][133];
    const int b = blockIdx.x;
    const int m = b & 7;
    const int rest = b >> 3;
    const int n = rest >> 6;
    const int h = rest & 63;
    const int tid = threadIdx.x;

    for (int idx = tid; idx < PW * 32; idx += 256) {
        const int r = idx >> 5;
        const int e = (idx & 31) * 4;
        const int code = codes[((n * PH + h) * PW + r) * PM + m];
        const float* src = codebook + ((size_t)m * PK + code) * PD + e;
#pragma unroll
        for (int j = 0; j < 4; ++j) rows[r][e + j] = src[j];
    }
    __syncthreads();

    const int w = tid & 63;
    const int cb0 = (tid >> 6) * 32;
    float* ob = out + (((size_t)n * (PM * PD) + m * PD + cb0) * PH + h) * PW + w;
    for (int ci = 0; ci < 32; ++ci) {
        const int c = cb0 + ci;
        const float* wr = wq + ((size_t)m * PD + c) * PD;
        float acc = bq[m * PD + c];
#pragma unroll 4
        for (int d = 0; d < PD; ++d) acc += rows[w][d] * wr[d];
        ob[(size_t)ci * (PH * PW)] = acc;
    }
}

extern "C" void kernel_launch(void* const* d_in, const int* in_sizes, int n_in,
                              void* d_out, int out_size, void* d_ws, size_t ws_size,
                              hipStream_t stream) {
    const int*   codes    = (const int*)  d_in[0];
    const float* codebook = (const float*)d_in[1];
    const float* wq       = (const float*)d_in[2];
    const float* bq       = (const float*)d_in[3];
    float* out = (float*)d_out;

    const size_t table_bytes = (size_t)PM * PK * PD * sizeof(unsigned short); // 8 MB
    if (ws_size >= table_bytes) {
        unsigned short* table = (unsigned short*)d_ws;
        build_table<<<dim3(256), dim3(256), 0, stream>>>(codebook, wq, bq, table);
        gather_scatter<<<dim3(PM * PN * PH), dim3(256), 0, stream>>>(codes, table, out);
    } else {
        fused_direct<<<dim3(PM * PN * PH), dim3(256), 0, stream>>>(codes, codebook, wq, bq, out);
    }
}

// Round 8
// 38.585 us; speedup vs baseline: 1.0276x; 1.0276x over previous
//
#include <hip/hip_runtime.h>
#include <hip/hip_bf16.h>

// Problem constants
#define PM 8        // groups
#define PK 4096     // codebook entries per group
#define PD 128      // dim
#define PN 8
#define PH 64
#define PW 64

typedef __attribute__((ext_vector_type(8))) short bf16x8;
typedef __attribute__((ext_vector_type(4))) float f32x4;
typedef __attribute__((ext_vector_type(8))) short short8v;

__device__ inline unsigned short f2bf_rne(float f) {
    unsigned int u = __float_as_uint(f);
    unsigned int r = (u + 0x7FFFu + ((u >> 16) & 1u)) >> 16;
    return (unsigned short)r;
}
__device__ inline float bf2f(unsigned short s) {
    return __uint_as_float(((unsigned int)s) << 16);
}

__device__ inline bf16x8 loadcvt8(const float* __restrict__ p) {
    f32x4 x0 = *(const f32x4*)p;
    f32x4 x1 = *(const f32x4*)(p + 4);
    bf16x8 r;
#pragma unroll
    for (int j = 0; j < 4; ++j) {
        r[j]     = (short)f2bf_rne(x0[j]);
        r[j + 4] = (short)f2bf_rne(x1[j]);
    }
    return r;
}

// ---------------------------------------------------------------------------
// Kernel 1 v3 (unchanged from R5, ~4 us): table[m,k,c] via LDS-staged wq,
// swapped-operand MFMA, packed 8 B stores.
// ---------------------------------------------------------------------------
__global__ __launch_bounds__(256) void build_table(
        const float* __restrict__ codebook,
        const float* __restrict__ wq,
        const float* __restrict__ bq,
        unsigned short* __restrict__ table) {
    __shared__ unsigned short ldsA[2048 * 8];   // 2048 frag-units x 16 B = 32 KB
    __shared__ float lds_bq[PD];
    const int b = blockIdx.x;
    const int m = b & 7;
    const int kt0 = (b >> 3) * 128;
    const int tid = threadIdx.x;
    const int wv = tid >> 6;
    const int l  = tid & 63;
    const int lr = l & 15;
    const int lg = l >> 4;

    const float* cb = codebook + (size_t)m * PK * PD;
    const float* wm = wq + (size_t)m * PD * PD;

    if (tid < PD) lds_bq[tid] = bq[m * PD + tid];

    // Stage wq -> LDS frag-major: unit u = (cs<<4)|(kk<<2)|lg holds
    // wq[cs*16 + slot][kk*32 + lg*8 .. +8) as bf16x8 at slot index.
    {
        const int lr_s = tid & 15;
        const int u0 = (tid >> 4) * 8;
#pragma unroll
        for (int i = 0; i < 8; ++i) {
            const int u  = u0 + i;
            const int cs = u >> 4;
            const int kk = (u >> 2) & 3;
            const int lgs = u & 3;
            bf16x8 v = loadcvt8(wm + (size_t)(cs * 16 + lr_s) * PD + kk * 32 + lgs * 8);
            *(bf16x8*)&ldsA[(size_t)(u * 16 + lr_s) * 8] = v;
        }
    }

    // Codebook B-frags (per-wave k rows), loaded while staging is in flight.
    bf16x8 bfragc[2][4];
#pragma unroll
    for (int ks = 0; ks < 2; ++ks) {
        const int k = kt0 + wv * 32 + ks * 16 + lr;
        const float* src = cb + (size_t)k * PD + lg * 8;
#pragma unroll
        for (int kk = 0; kk < 4; ++kk) {
            bfragc[ks][kk] = loadcvt8(src + kk * 32);
        }
    }
    __syncthreads();

#pragma unroll
    for (int cs = 0; cs < 8; ++cs) {
        bf16x8 afragw[4];
#pragma unroll
        for (int kk = 0; kk < 4; ++kk) {
            const int u = (cs << 4) | (kk << 2) | lg;
            afragw[kk] = *(const bf16x8*)&ldsA[(size_t)(u * 16 + lr) * 8];
        }
        const f32x4 bias4 = *(const f32x4*)&lds_bq[cs * 16 + lg * 4];
#pragma unroll
        for (int ks = 0; ks < 2; ++ks) {
            f32x4 acc = {0.f, 0.f, 0.f, 0.f};
#pragma unroll
            for (int kk = 0; kk < 4; ++kk) {
                acc = __builtin_amdgcn_mfma_f32_16x16x32_bf16(
                        afragw[kk], bfragc[ks][kk], acc, 0, 0, 0);
            }
            // D[row = c = cs*16 + lg*4 + j][col = k = kt0+wv*32+ks*16+lr]
            const int k = kt0 + wv * 32 + ks * 16 + lr;
            unsigned int p0 = (unsigned int)f2bf_rne(acc[0] + bias4[0])
                            | ((unsigned int)f2bf_rne(acc[1] + bias4[1]) << 16);
            unsigned int p1 = (unsigned int)f2bf_rne(acc[2] + bias4[2])
                            | ((unsigned int)f2bf_rne(acc[3] + bias4[3]) << 16);
            uint2 pk; pk.x = p0; pk.y = p1;
            *(uint2*)&table[((size_t)(m * PK + k)) * PD + cs * 16 + lg * 4] = pk;
        }
    }
}

// ---------------------------------------------------------------------------
// Kernel 2 v7: coop gather -> LDS transpose -> dwordx4 stores (fill-parity).
// The ONLY untested axis left: store instr width/count. All variants so far
// issued 4-8 B/lane stores (32 instrs/thread); the 6.8 TB/s fill issues
// 16 B/lane dwordx4. This version: 8 store instrs/thread, 16 B/lane,
// each instr = 4 x 256 B full segments, at full TLP (4096 blocks).
// Phase 1 (R7 coop gather): thread (p=tid>>2, sub=tid&3) reads 4x16 B, the
//   4 sub-lanes covering one 64 B line per chunk-index; writes f32 LDS
//   transpose [c][w] stride 65: write banks (8*sub+jj+p)%32 exact 2-way
//   (free, m136); b128 reads hit the 8-beat data floor (layout-optimal).
// Phase 2: thread (cq=tid>>4, wq=tid&15): 8 x { ds_read_b128 + plain
//   global_store_dwordx4 } to out[n, m*128+c, h, wq*4..+4).
// LDS 33.3 KB -> 4 blocks/CU = 16 waves/CU (R6: this occupancy is fine).
// m = b&7 keeps each XCD on its 1 MB table slice.
// ---------------------------------------------------------------------------
__global__ __launch_bounds__(256) void gather_scatter(
        const int* __restrict__ codes,
        const unsigned short* __restrict__ table,
        float* __restrict__ out) {
    __shared__ float ldsF[PD * 65];
    const int b = blockIdx.x;
    const int m = b & 7;
    const int rest = b >> 3;
    const int n = rest >> 6;
    const int h = rest & 63;
    const int tid = threadIdx.x;

    // ---- Phase 1: cooperative gather, transpose into LDS [c][w] ----
    {
        const int p   = tid >> 2;   // position (w) 0..63
        const int sub = tid & 3;    // 16 B sub-chunk within each 64 B line
        const int code = codes[((n * PH + h) * PW + p) * PM + m];
        const unsigned short* row = table + ((size_t)m * PK + code) * PD;
        short8v v[4];
#pragma unroll
        for (int i = 0; i < 4; ++i) {
            v[i] = *(const short8v*)(row + i * 32 + sub * 8);
        }
#pragma unroll
        for (int i = 0; i < 4; ++i) {
#pragma unroll
            for (int jj = 0; jj < 8; ++jj) {
                const int c = i * 32 + sub * 8 + jj;
                ldsF[c * 65 + p] = bf2f((unsigned short)v[i][jj]);
            }
        }
    }
    __syncthreads();

    // ---- Phase 2: b128 LDS reads + dwordx4 coalesced stores ----
    const int cq = tid >> 4;    // 0..15 -> c = cq*8 + j
    const int wq = tid & 15;    // w = wq*4 .. +4
    float* ob = out + (((size_t)n * (PM * PD) + m * PD + cq * 8) * PH + h) * PW + wq * 4;
#pragma unroll
    for (int j = 0; j < 8; ++j) {
        const int c = cq * 8 + j;
        f32x4 val = *(const f32x4*)&ldsF[c * 65 + wq * 4];
        *(f32x4*)(ob + (size_t)j * (PH * PW)) = val;
    }
}

// ---------------------------------------------------------------------------
// Fallback (only if ws_size < table size): fused direct compute, fp32.
// ---------------------------------------------------------------------------
__global__ __launch_bounds__(256) void fused_direct(
        const int* __restrict__ codes,
        const float* __restrict__ codebook,
        const float* __restrict__ wq,
        const float* __restrict__ bq,
        float* __restrict__ out) {
    __shared__ float rows[PW][133];
    const int b = blockIdx.x;
    const int m = b & 7;
    const int rest = b >> 3;
    const int n = rest >> 6;
    const int h = rest & 63;
    const int tid = threadIdx.x;

    for (int idx = tid; idx < PW * 32; idx += 256) {
        const int r = idx >> 5;
        const int e = (idx & 31) * 4;
        const int code = codes[((n * PH + h) * PW + r) * PM + m];
        const float* src = codebook + ((size_t)m * PK + code) * PD + e;
#pragma unroll
        for (int j = 0; j < 4; ++j) rows[r][e + j] = src[j];
    }
    __syncthreads();

    const int w = tid & 63;
    const int cb0 = (tid >> 6) * 32;
    float* ob = out + (((size_t)n * (PM * PD) + m * PD + cb0) * PH + h) * PW + w;
    for (int ci = 0; ci < 32; ++ci) {
        const int c = cb0 + ci;
        const float* wr = wq + ((size_t)m * PD + c) * PD;
        float acc = bq[m * PD + c];
#pragma unroll 4
        for (int d = 0; d < PD; ++d) acc += rows[w][d] * wr[d];
        ob[(size_t)ci * (PH * PW)] = acc;
    }
}

extern "C" void kernel_launch(void* const* d_in, const int* in_sizes, int n_in,
                              void* d_out, int out_size, void* d_ws, size_t ws_size,
                              hipStream_t stream) {
    const int*   codes    = (const int*)  d_in[0];
    const float* codebook = (const float*)d_in[1];
    const float* wq       = (const float*)d_in[2];
    const float* bq       = (const float*)d_in[3];
    float* out = (float*)d_out;

    const size_t table_bytes = (size_t)PM * PK * PD * sizeof(unsigned short); // 8 MB
    if (ws_size >= table_bytes) {
        unsigned short* table = (unsigned short*)d_ws;
        build_table<<<dim3(256), dim3(256), 0, stream>>>(codebook, wq, bq, table);
        gather_scatter<<<dim3(PM * PN * PH), dim3(256), 0, stream>>>(codes, table, out);
    } else {
        fused_direct<<<dim3(PM * PN * PH), dim3(256), 0, stream>>>(codes, codebook, wq, bq, out);
    }
}